// Round 7
// baseline (557.660 us; speedup 1.0000x reference)
//
#include <hip/hip_runtime.h>

// Problem constants (fixed by setup_inputs)
#define NT    8           // timesteps
#define NB    16          // batch
#define FS    262144      // C*H*W (= 2^18)
#define TPB   256         // threads per block
#define BPB   64          // blocks per batch (gather = exactly one wave)
#define GRID  (NB*BPB)    // 1024 blocks = 4/CU
#define CHK   4           // float4 chunks/thread -> 16 elems/thread
#define ELB   (TPB*CHK*4) // 4096 elems per block
#define SPIN_CAP (1L<<26)

// ws layout (zeroed every launch):
//   bsum double[NT][NB][BPB] @ 0     (65536 B) per-block |m| sums, stored -bs
//        (slot0 of bsum[t-1][b] is REUSED as round-t denominator broadcast:
//         causally dead when written; stale -bs <= -0 vs dn > 0 is flag-safe.
//         bytes +16.. of each region are later reused for count ints.)
//   ctrl @ 65536 (1024 B): per-batch 64B lines:
//        [b*64 + 0]  int    monotone arrival counter (64 per round, never reset;
//                           round t target old==64*t+63; count round old==575)
//        [b*64 + 8]  double round-0 denominator broadcast home
#define CTRL_OFF 65536
#define WS_NEED  66560

__device__ __forceinline__ void bar_lds() {
    // raw workgroup barrier draining ONLY LDS (lgkmcnt). Unlike __syncthreads
    // it does NOT wait vmcnt(0), so in-flight global prefetches ride through.
    __builtin_amdgcn_sched_barrier(0);
    asm volatile("s_waitcnt lgkmcnt(0)" ::: "memory");
    __builtin_amdgcn_s_barrier();
    __builtin_amdgcn_sched_barrier(0);
}

__device__ __forceinline__ double* dbc_ptr(char* wsb, int t, int b) {
    // round-t denominator broadcast home (also count-total home, negated)
    return (t == 0) ? (double*)(wsb + CTRL_OFF + b * 64 + 8)
                    : (double*)wsb + (size_t)((t - 1) * NB + b) * BPB;
}

__global__ __launch_bounds__(TPB, 4)
void bispike_kernel(const float* __restrict__ x,
                    const float* __restrict__ decay_p,
                    const float* __restrict__ vth_p,
                    const float* __restrict__ W1,
                    const float* __restrict__ b1,
                    const float* __restrict__ W2,
                    const float* __restrict__ b2,
                    const float* __restrict__ att_w,
                    float* __restrict__ out,
                    char* __restrict__ wsb)
{
    const int tid  = threadIdx.x;
    const int lane = tid & 63;
    const int wid  = tid >> 6;
    const int b    = blockIdx.x & 15;   // XCD-localized batches
    const int bg   = blockIdx.x >> 4;

    int* ctr_b = (int*)(wsb + CTRL_OFF + b * 64);

    const double dec  = 1.0 / (1.0 + exp(-(double)decay_p[0]));
    const double vth  = (double)vth_p[0];
    const double csub = dec * vth;

    double   u[CHK * 4];
    float4   xv[CHK];
    unsigned sm[NT];

    {
        const float* p = x + (size_t)b * FS + (size_t)bg * ELB + tid * 4;
        #pragma unroll
        for (int k = 0; k < CHK; ++k) xv[k] = *(const float4*)(p + k * (TPB * 4));
    }
    double lsum;
    {
        double n0 = 0.0, n1 = 0.0, n2 = 0.0, n3 = 0.0;
        #pragma unroll
        for (int k = 0; k < CHK; ++k) {
            u[k*4+0] = (double)xv[k].x; n0 += fabs(u[k*4+0]);
            u[k*4+1] = (double)xv[k].y; n1 += fabs(u[k*4+1]);
            u[k*4+2] = (double)xv[k].z; n2 += fabs(u[k*4+2]);
            u[k*4+3] = (double)xv[k].w; n3 += fabs(u[k*4+3]);
        }
        lsum = (n0 + n1) + (n2 + n3);
    }

    __shared__ double dred[4];
    __shared__ double denom_s;

    #pragma unroll 1
    for (int t = 0; t < NT; ++t) {
        // waves 1-3: early prefetch (rides through the raw barriers)
        if (wid != 0 && t < NT - 1) {
            const float* p = x + ((size_t)(t + 1) * NB + b) * FS
                               + (size_t)bg * ELB + tid * 4;
            #pragma unroll
            for (int k = 0; k < CHK; ++k) xv[k] = *(const float4*)(p + k * (TPB * 4));
        }

        // ---- wave partial of sum |m_t| ----
        double ls = lsum;
        #pragma unroll
        for (int off = 32; off > 0; off >>= 1)
            ls += __shfl_down(ls, off, 64);
        if (lane == 0) dred[wid] = ls;
        bar_lds();                        // LDS-only drain: publish not delayed

        if (wid == 0) {
            const double bs = (dred[0] + dred[1]) + (dred[2] + dred[3]);
            double* slot = (double*)wsb + (size_t)(t * NB + b) * BPB;
            double* dbc  = dbc_ptr(wsb, t, b);
            int o_ = -1;
            if (lane == 0) {
                __hip_atomic_store(slot + bg, -bs, __ATOMIC_RELAXED,
                                   __HIP_MEMORY_SCOPE_AGENT);
                // release orders the slot store before the counter bump;
                // acquire (for the last arriver) makes all slots visible.
                o_ = __hip_atomic_fetch_add(ctr_b, 1, __ATOMIC_ACQ_REL,
                                            __HIP_MEMORY_SCOPE_AGENT);
            }
            const int oo = __shfl(o_, 0, 64);
            double dn = 0.0;
            if (oo == 64 * t + 63) {
                // LAST ARRIVER: zero-latency detection; wave-gather 64 slots,
                // same shfl tree as before -> bit-identical denominator.
                double v = __hip_atomic_load(slot + lane, __ATOMIC_RELAXED,
                                             __HIP_MEMORY_SCOPE_AGENT);
                double tot = (lane == bg) ? bs : -v;
                #pragma unroll
                for (int off = 32; off > 0; off >>= 1)
                    tot += __shfl_down(tot, off, 64);
                if (lane == 0) {
                    dn = tot / (double)FS + 1e-6;     // mean exact /2^18
                    __hip_atomic_store(dbc, dn, __ATOMIC_RELAXED,
                                       __HIP_MEMORY_SCOPE_AGENT);
                }
            }
            // wave0 prefetch after publish/gather issue
            if (t < NT - 1) {
                const float* p = x + ((size_t)(t + 1) * NB + b) * FS
                                   + (size_t)bg * ELB + tid * 4;
                #pragma unroll
                for (int k = 0; k < CHK; ++k)
                    xv[k] = *(const float4*)(p + k * (TPB * 4));
            }
            if (lane == 0) {
                if (oo != 64 * t + 63) {
                    long it = 0;
                    for (;;) {
                        dn = __hip_atomic_load(dbc, __ATOMIC_RELAXED,
                                               __HIP_MEMORY_SCOPE_AGENT);
                        if (dn > 0.0) break;          // stale is -bs <= -0
                        if (++it > SPIN_CAP) break;
                        __builtin_amdgcn_s_sleep(2);
                    }
                }
                denom_s = dn;
            }
        }
        bar_lds();                        // LDS-only drain again
        const double denom = denom_s;

        // fused threshold + advance:
        //   s_t = (u >= vth*D_t);  u' = (dec/D_t)*u + x' - s_t*(dec*vth)
        const double thr = vth * denom;
        const double a   = dec * (1.0 / denom);
        unsigned smt = 0;
        if (t < NT - 1) {
            double n0 = 0.0, n1 = 0.0, n2 = 0.0, n3 = 0.0;
            #pragma unroll
            for (int k = 0; k < CHK; ++k) {
                const double xn0 = (double)xv[k].x, xn1 = (double)xv[k].y,
                             xn2 = (double)xv[k].z, xn3 = (double)xv[k].w;
                double un;
                bool s0 = (u[k*4+0] >= thr); if (s0) smt |= 1u << (k*4+0);
                un = fma(a, u[k*4+0], xn0); if (s0) un -= csub;
                u[k*4+0] = un; n0 += fabs(un);
                bool s1 = (u[k*4+1] >= thr); if (s1) smt |= 1u << (k*4+1);
                un = fma(a, u[k*4+1], xn1); if (s1) un -= csub;
                u[k*4+1] = un; n1 += fabs(un);
                bool s2 = (u[k*4+2] >= thr); if (s2) smt |= 1u << (k*4+2);
                un = fma(a, u[k*4+2], xn2); if (s2) un -= csub;
                u[k*4+2] = un; n2 += fabs(un);
                bool s3 = (u[k*4+3] >= thr); if (s3) smt |= 1u << (k*4+3);
                un = fma(a, u[k*4+3], xn3); if (s3) un -= csub;
                u[k*4+3] = un; n3 += fabs(un);
            }
            lsum = (n0 + n1) + (n2 + n3);
        } else {
            #pragma unroll
            for (int j = 0; j < CHK * 4; ++j)
                if (u[j] >= thr) smt |= 1u << j;
        }
        sm[t] = smt;
    }

    // ---- spike counts per (t,b): exact ints, last-arriver protocol ----
    __shared__ int ired[NT][4];
    #pragma unroll
    for (int t = 0; t < NT; ++t) {
        int c = __popc(sm[t]);
        #pragma unroll
        for (int off = 32; off > 0; off >>= 1)
            c += __shfl_down(c, off, 64);
        if (lane == 0) ired[t][wid] = c;
    }
    __syncthreads();                      // cold path: plain barrier fine

    __shared__ int totc_s[NT];
    __shared__ double summ_s[NT];

    if (wid == 0) {
        // count ints live at bytes +16.. of each (now-dead) bsum region,
        // clear of the slot0 broadcast homes.
        if (lane < NT) {
            int tot = (ired[lane][0] + ired[lane][1])
                    + (ired[lane][2] + ired[lane][3]);
            int* ip = (int*)(wsb + (size_t)(lane * NB + b) * 512 + 16 + bg * 4);
            __hip_atomic_store(ip, tot, __ATOMIC_RELAXED,
                               __HIP_MEMORY_SCOPE_AGENT);
        }
        int o_ = -1;
        if (lane == 0)
            o_ = __hip_atomic_fetch_add(ctr_b, 1, __ATOMIC_ACQ_REL,
                                        __HIP_MEMORY_SCOPE_AGENT);
        const int oo = __shfl(o_, 0, 64);
        if (oo == 64 * NT + 63) {
            #pragma unroll 1
            for (int t = 0; t < NT; ++t) {
                int v = __hip_atomic_load(
                            (int*)(wsb + (size_t)(t * NB + b) * 512 + 16 + lane * 4),
                            __ATOMIC_RELAXED, __HIP_MEMORY_SCOPE_AGENT);
                #pragma unroll
                for (int off = 32; off > 0; off >>= 1)
                    v += __shfl_down(v, off, 64);
                if (lane == 0)
                    __hip_atomic_store(dbc_ptr(wsb, t, b), -(double)(v + 1),
                                       __ATOMIC_RELAXED, __HIP_MEMORY_SCOPE_AGENT);
            }
        }
        if (lane < NT) {
            double cv; long it = 0;
            for (;;) {
                cv = __hip_atomic_load(dbc_ptr(wsb, lane, b), __ATOMIC_RELAXED,
                                       __HIP_MEMORY_SCOPE_AGENT);
                if (cv < 0.0) break;      // stale is dn > 0
                if (++it > SPIN_CAP) break;
                __builtin_amdgcn_s_sleep(2);
            }
            totc_s[lane] = (int)(-cv) - 1;
        }
    }
    __syncthreads();
    if (tid < NT)
        summ_s[tid] = (double)totc_s[tid] / (double)FS;    // exact
    __syncthreads();

    // ---- tiny MLP attention in fp64, redundantly per block ----
    __shared__ double h_s[4 * 64];
    __shared__ double wmat_s[NT];
    {
        int nh = tid >> 6, hd = tid & 63;
        double acc = 0.0;
        #pragma unroll
        for (int t = 0; t < NT; ++t)
            acc += summ_s[t] * (double)W1[nh * 512 + hd * 8 + t];
        acc += (double)b1[nh * 64 + hd];
        h_s[tid] = fmax(acc, 0.0);
    }
    __syncthreads();
    if (tid < NT) {
        double w = 0.0;
        for (int nh = 0; nh < 4; ++nh) {
            double macc = 0.0;
            for (int hd = 0; hd < 64; ++hd)
                macc += h_s[nh * 64 + hd] * (double)W2[nh * 512 + tid * 64 + hd];
            macc += (double)b2[nh * 8 + tid];
            w += macc * (double)att_w[nh];
        }
        wmat_s[tid] = w;
    }
    __syncthreads();

    double awr[NT];
    {
        double mx = wmat_s[0];
        #pragma unroll
        for (int t = 1; t < NT; ++t) mx = fmax(mx, wmat_s[t]);
        double ss = 0.0;
        #pragma unroll
        for (int t = 0; t < NT; ++t) { awr[t] = exp(wmat_s[t] - mx); ss += awr[t]; }
        #pragma unroll
        for (int t = 0; t < NT; ++t) awr[t] = awr[t] / ss;
    }

    float* po = out + (size_t)b * FS + (size_t)bg * ELB + tid * 4;
    #pragma unroll
    for (int k = 0; k < CHK; ++k) {
        double o[4] = {0.0, 0.0, 0.0, 0.0};
        #pragma unroll
        for (int t = 0; t < NT; ++t) {
            const unsigned smt = sm[t];
            o[0] += ((smt >> (k * 4 + 0)) & 1) ? awr[t] : 0.0;
            o[1] += ((smt >> (k * 4 + 1)) & 1) ? awr[t] : 0.0;
            o[2] += ((smt >> (k * 4 + 2)) & 1) ? awr[t] : 0.0;
            o[3] += ((smt >> (k * 4 + 3)) & 1) ? awr[t] : 0.0;
        }
        *(float4*)(po + k * (TPB * 4)) =
            make_float4((float)o[0], (float)o[1], (float)o[2], (float)o[3]);
    }
}

__global__ void diag_kernel(float* out, int code) {
    out[0] = 100000.0f + (float)code;
}

extern "C" void kernel_launch(void* const* d_in, const int* in_sizes, int n_in,
                              void* d_out, int out_size, void* d_ws, size_t ws_size,
                              hipStream_t stream) {
    const float* x     = (const float*)d_in[0];
    const float* decay = (const float*)d_in[1];
    const float* vth   = (const float*)d_in[2];
    const float* W1    = (const float*)d_in[3];
    const float* b1    = (const float*)d_in[4];
    const float* W2    = (const float*)d_in[5];
    const float* b2    = (const float*)d_in[6];
    const float* att   = (const float*)d_in[7];
    float* out = (float*)d_out;

    if (ws_size < WS_NEED) {
        diag_kernel<<<1, 1, 0, stream>>>(out, 999);
        return;
    }

    hipMemsetAsync(d_ws, 0, WS_NEED, stream);

    hipGetLastError();  // clear stale error
    bispike_kernel<<<dim3(GRID), dim3(TPB), 0, stream>>>(
        x, decay, vth, W1, b1, W2, b2, att, out, (char*)d_ws);
    hipError_t err = hipGetLastError();
    if (err != hipSuccess) {
        diag_kernel<<<1, 1, 0, stream>>>(out, (int)err);
    }
}

// Round 8
// 232.119 us; speedup vs baseline: 2.4025x; 2.4025x over previous
//
#include <hip/hip_runtime.h>

// Problem constants (fixed by setup_inputs)
#define NT    8           // timesteps
#define NB    16          // batch
#define FS    262144      // C*H*W (= 2^18)
#define TPB   256         // threads per block
#define BPB   64          // blocks per batch
#define GRID  (NB*BPB)    // 1024 blocks = 4/CU
#define CHK   4           // float4 chunks/thread -> 16 elems/thread
#define ELB   (TPB*CHK*4) // 4096 elems per block
#define SPIN_CAP (1L<<26)

// Fence-free bias-carrying accumulators (all atomics RELAXED — no L2
// writeback/invalidate, the R7 killer):
//   each block adds (payload + BIAS); BIAS doubles as arrival counter.
//   value >= 64*BIAS  <=>  all 64 blocks arrived (no early trigger:
//   63*K + max Sum(bs) << 64*K; 63*BI + max Sum(cnt) < 64*BI).
#define K_BIAS  67108864.0          // 2^26  (fp64 partials; bs <= ~8e4)
#define TGT_D   4294967296.0        // 64*K = 2^32, exactly representable
#define B_BIAS  524288              // 2^19  (int counts; cnt <= 4096)
#define TGT_I   33554432            // 64*B = 2^25

// ws layout (zeroed every launch), all slots padded to own 64B line:
//   acc double @ (t*NB+b)*64           8 KB   |m|-sum accumulators
//   cnt int    @ 8192 + (t*NB+b)*64    8 KB   spike-count accumulators
#define WS_NEED 16384

__device__ __forceinline__ void bar_lds() {
    // raw workgroup barrier draining ONLY LDS (lgkmcnt): in-flight global
    // prefetches ride through (unlike __syncthreads' vmcnt(0) drain).
    __builtin_amdgcn_sched_barrier(0);
    asm volatile("s_waitcnt lgkmcnt(0)" ::: "memory");
    __builtin_amdgcn_s_barrier();
    __builtin_amdgcn_sched_barrier(0);
}

__global__ __launch_bounds__(TPB, 4)
void bispike_kernel(const float* __restrict__ x,
                    const float* __restrict__ decay_p,
                    const float* __restrict__ vth_p,
                    const float* __restrict__ W1,
                    const float* __restrict__ b1,
                    const float* __restrict__ W2,
                    const float* __restrict__ b2,
                    const float* __restrict__ att_w,
                    float* __restrict__ out,
                    char* __restrict__ wsb)
{
    const int tid  = threadIdx.x;
    const int lane = tid & 63;
    const int wid  = tid >> 6;
    const int b    = blockIdx.x & 15;   // XCD-localized batches
    const int bg   = blockIdx.x >> 4;

    const double dec  = 1.0 / (1.0 + exp(-(double)decay_p[0]));
    const double vth  = (double)vth_p[0];
    const double csub = dec * vth;      // loop-invariant spike correction

    double   u[CHK * 4];                // unnormalized membrane m_t (fp64)
    float4   xv[CHK];                   // prefetched x (fp32 in memory)
    unsigned sm[NT];                    // spike bits (16 used)

    {   // t=0: m_0 = x_0 (carry is zero)
        const float* p = x + (size_t)b * FS + (size_t)bg * ELB + tid * 4;
        #pragma unroll
        for (int k = 0; k < CHK; ++k) xv[k] = *(const float4*)(p + k * (TPB * 4));
    }
    double lsum;
    {
        double n0 = 0.0, n1 = 0.0, n2 = 0.0, n3 = 0.0;
        #pragma unroll
        for (int k = 0; k < CHK; ++k) {
            u[k*4+0] = (double)xv[k].x; n0 += fabs(u[k*4+0]);
            u[k*4+1] = (double)xv[k].y; n1 += fabs(u[k*4+1]);
            u[k*4+2] = (double)xv[k].z; n2 += fabs(u[k*4+2]);
            u[k*4+3] = (double)xv[k].w; n3 += fabs(u[k*4+3]);
        }
        lsum = (n0 + n1) + (n2 + n3);
    }

    __shared__ double dred[4];
    __shared__ double denom_s;

    #pragma unroll 1
    for (int t = 0; t < NT; ++t) {
        // waves 1-3: early prefetch (rides through the raw barriers)
        if (wid != 0 && t < NT - 1) {
            const float* p = x + ((size_t)(t + 1) * NB + b) * FS
                               + (size_t)bg * ELB + tid * 4;
            #pragma unroll
            for (int k = 0; k < CHK; ++k) xv[k] = *(const float4*)(p + k * (TPB * 4));
        }

        // ---- wave partial of sum |m_t| ----
        double ls = lsum;
        #pragma unroll
        for (int off = 32; off > 0; off >>= 1)
            ls += __shfl_down(ls, off, 64);
        if (lane == 0) dred[wid] = ls;
        bar_lds();

        if (wid == 0) {
            const double bs = (dred[0] + dred[1]) + (dred[2] + dred[3]);
            if (lane == 0) {
                // single relaxed RMW: payload + bias; bias counts arrivals.
                // wave0 has NO loads in flight (prefetch deferred) -> the
                // returned old value and poll loads are not FIFO-delayed.
                double* acc = (double*)(wsb + (size_t)(t * NB + b) * 64);
                double ret = __hip_atomic_fetch_add(acc, bs + K_BIAS,
                                 __ATOMIC_RELAXED, __HIP_MEMORY_SCOPE_AGENT);
                double v = ret + (bs + K_BIAS);
                if (v < TGT_D - 1.0) {          // not last: poll (payload=flag)
                    long it = 0;
                    for (;;) {
                        v = __hip_atomic_load(acc, __ATOMIC_RELAXED,
                                              __HIP_MEMORY_SCOPE_AGENT);
                        if (v >= TGT_D - 1.0) break;
                        if (++it > SPIN_CAP) break;
                        __builtin_amdgcn_s_sleep(2);
                    }
                }
                // mean exact /2^18; atomic-order+bias perturbation ~2e-10 rel
                denom_s = (v - TGT_D) / (double)FS + 1e-6;
            }
            // wave0 prefetch deferred until protocol done
            if (t < NT - 1) {
                const float* p = x + ((size_t)(t + 1) * NB + b) * FS
                                   + (size_t)bg * ELB + tid * 4;
                #pragma unroll
                for (int k = 0; k < CHK; ++k)
                    xv[k] = *(const float4*)(p + k * (TPB * 4));
            }
        }
        bar_lds();
        const double denom = denom_s;

        // fused threshold + advance:
        //   s_t = (u >= vth*D_t);  u' = (dec/D_t)*u + x' - s_t*(dec*vth)
        const double thr = vth * denom;
        const double a   = dec * (1.0 / denom);
        unsigned smt = 0;
        if (t < NT - 1) {
            double n0 = 0.0, n1 = 0.0, n2 = 0.0, n3 = 0.0;
            #pragma unroll
            for (int k = 0; k < CHK; ++k) {
                const double xn0 = (double)xv[k].x, xn1 = (double)xv[k].y,
                             xn2 = (double)xv[k].z, xn3 = (double)xv[k].w;
                double un;
                bool s0 = (u[k*4+0] >= thr); if (s0) smt |= 1u << (k*4+0);
                un = fma(a, u[k*4+0], xn0); if (s0) un -= csub;
                u[k*4+0] = un; n0 += fabs(un);
                bool s1 = (u[k*4+1] >= thr); if (s1) smt |= 1u << (k*4+1);
                un = fma(a, u[k*4+1], xn1); if (s1) un -= csub;
                u[k*4+1] = un; n1 += fabs(un);
                bool s2 = (u[k*4+2] >= thr); if (s2) smt |= 1u << (k*4+2);
                un = fma(a, u[k*4+2], xn2); if (s2) un -= csub;
                u[k*4+2] = un; n2 += fabs(un);
                bool s3 = (u[k*4+3] >= thr); if (s3) smt |= 1u << (k*4+3);
                un = fma(a, u[k*4+3], xn3); if (s3) un -= csub;
                u[k*4+3] = un; n3 += fabs(un);
            }
            lsum = (n0 + n1) + (n2 + n3);
        } else {
            #pragma unroll
            for (int j = 0; j < CHK * 4; ++j)
                if (u[j] >= thr) smt |= 1u << j;
        }
        sm[t] = smt;
    }

    // ---- spike counts per (t,b): exact ints, same fence-free protocol ----
    __shared__ int ired[NT][4];
    #pragma unroll
    for (int t = 0; t < NT; ++t) {
        int c = __popc(sm[t]);
        #pragma unroll
        for (int off = 32; off > 0; off >>= 1)
            c += __shfl_down(c, off, 64);
        if (lane == 0) ired[t][wid] = c;
    }
    __syncthreads();

    __shared__ int totc_s[NT];
    __shared__ double summ_s[NT];

    if (wid == 0) {
        int* cp = (int*)(wsb + 8192 + (size_t)(lane * NB + b) * 64);
        int v = TGT_I;                   // lanes >= NT: already "done"
        if (lane < NT) {
            int tot = (ired[lane][0] + ired[lane][1])
                    + (ired[lane][2] + ired[lane][3]);
            int ret = __hip_atomic_fetch_add(cp, tot + B_BIAS,
                          __ATOMIC_RELAXED, __HIP_MEMORY_SCOPE_AGENT);
            v = ret + tot + B_BIAS;
        }
        long it = 0;
        while (!__all(v >= TGT_I)) {
            if (lane < NT && v < TGT_I)
                v = __hip_atomic_load(cp, __ATOMIC_RELAXED,
                                      __HIP_MEMORY_SCOPE_AGENT);
            if (++it > SPIN_CAP) break;
            __builtin_amdgcn_s_sleep(2);
        }
        if (lane < NT) totc_s[lane] = v - TGT_I;   // exact int total
    }
    __syncthreads();
    if (tid < NT)
        summ_s[tid] = (double)totc_s[tid] / (double)FS;    // exact
    __syncthreads();

    // ---- tiny MLP attention in fp64, redundantly per block ----
    __shared__ double h_s[4 * 64];
    __shared__ double wmat_s[NT];
    {
        int nh = tid >> 6, hd = tid & 63;
        double acc = 0.0;
        #pragma unroll
        for (int t = 0; t < NT; ++t)
            acc += summ_s[t] * (double)W1[nh * 512 + hd * 8 + t];
        acc += (double)b1[nh * 64 + hd];
        h_s[tid] = fmax(acc, 0.0);
    }
    __syncthreads();
    if (tid < NT) {
        double w = 0.0;
        for (int nh = 0; nh < 4; ++nh) {
            double macc = 0.0;
            for (int hd = 0; hd < 64; ++hd)
                macc += h_s[nh * 64 + hd] * (double)W2[nh * 512 + tid * 64 + hd];
            macc += (double)b2[nh * 8 + tid];
            w += macc * (double)att_w[nh];
        }
        wmat_s[tid] = w;
    }
    __syncthreads();

    // softmax over t in fp64 (per-thread copy)
    double awr[NT];
    {
        double mx = wmat_s[0];
        #pragma unroll
        for (int t = 1; t < NT; ++t) mx = fmax(mx, wmat_s[t]);
        double ss = 0.0;
        #pragma unroll
        for (int t = 0; t < NT; ++t) { awr[t] = exp(wmat_s[t] - mx); ss += awr[t]; }
        #pragma unroll
        for (int t = 0; t < NT; ++t) awr[t] = awr[t] / ss;
    }

    // ---- out[b,f] = sum_t spike_bit * aw[t,b] (fp64 acc, fp32 store) ----
    float* po = out + (size_t)b * FS + (size_t)bg * ELB + tid * 4;
    #pragma unroll
    for (int k = 0; k < CHK; ++k) {
        double o[4] = {0.0, 0.0, 0.0, 0.0};
        #pragma unroll
        for (int t = 0; t < NT; ++t) {
            const unsigned smt = sm[t];
            o[0] += ((smt >> (k * 4 + 0)) & 1) ? awr[t] : 0.0;
            o[1] += ((smt >> (k * 4 + 1)) & 1) ? awr[t] : 0.0;
            o[2] += ((smt >> (k * 4 + 2)) & 1) ? awr[t] : 0.0;
            o[3] += ((smt >> (k * 4 + 3)) & 1) ? awr[t] : 0.0;
        }
        *(float4*)(po + k * (TPB * 4)) =
            make_float4((float)o[0], (float)o[1], (float)o[2], (float)o[3]);
    }
}

__global__ void diag_kernel(float* out, int code) {
    out[0] = 100000.0f + (float)code;
}

extern "C" void kernel_launch(void* const* d_in, const int* in_sizes, int n_in,
                              void* d_out, int out_size, void* d_ws, size_t ws_size,
                              hipStream_t stream) {
    const float* x     = (const float*)d_in[0];
    const float* decay = (const float*)d_in[1];
    const float* vth   = (const float*)d_in[2];
    const float* W1    = (const float*)d_in[3];
    const float* b1    = (const float*)d_in[4];
    const float* W2    = (const float*)d_in[5];
    const float* b2    = (const float*)d_in[6];
    const float* att   = (const float*)d_in[7];
    float* out = (float*)d_out;

    if (ws_size < WS_NEED) {
        diag_kernel<<<1, 1, 0, stream>>>(out, 999);
        return;
    }

    hipMemsetAsync(d_ws, 0, WS_NEED, stream);

    hipGetLastError();  // clear stale error
    bispike_kernel<<<dim3(GRID), dim3(TPB), 0, stream>>>(
        x, decay, vth, W1, b1, W2, b2, att, out, (char*)d_ws);
    hipError_t err = hipGetLastError();
    if (err != hipSuccess) {
        diag_kernel<<<1, 1, 0, stream>>>(out, (int)err);
    }
}

// Round 9
// 228.258 us; speedup vs baseline: 2.4431x; 1.0169x over previous
//
#include <hip/hip_runtime.h>

// Problem constants (fixed by setup_inputs)
#define NT    8           // timesteps
#define NB    16          // batch
#define FS    262144      // C*H*W (= 2^18)
#define TPB   512         // threads per block (8 waves)
#define NW    8           // waves per block
#define BPB   16          // blocks per batch
#define GRID  (NB*BPB)    // 256 blocks = EXACTLY 1 per CU (kills co-residency smear)
#define CHK   8           // float4 chunks/thread -> 32 elems/thread
#define ELB   (TPB*CHK*4) // 16384 elems per block
#define SPIN_CAP (1L<<26)

// Fence-free bias-carrying accumulators (all atomics RELAXED):
//   each block adds (payload + BIAS); BIAS doubles as arrival counter.
//   16 arrivals: value >= 16*BIAS. No early trigger: 15*K + max Sum(bs)
//   (~1e6) << 2^30; 15*B + max Sum(cnt) (2^18) < 2^23.
#define K_BIAS  67108864.0          // 2^26
#define TGT_D   1073741824.0        // 16*K = 2^30, exactly representable
#define B_BIAS  524288              // 2^19
#define TGT_I   8388608             // 16*B = 2^23

// ws layout (zeroed every launch), all slots padded to own 64B line:
//   acc double @ (t*NB+b)*64           8 KB   |m|-sum accumulators
//   cnt int    @ 8192 + (t*NB+b)*64    8 KB   spike-count accumulators
#define WS_NEED 16384

__device__ __forceinline__ void bar_lds() {
    // raw workgroup barrier draining ONLY LDS (lgkmcnt): in-flight global
    // prefetches ride through (unlike __syncthreads' vmcnt(0) drain).
    __builtin_amdgcn_sched_barrier(0);
    asm volatile("s_waitcnt lgkmcnt(0)" ::: "memory");
    __builtin_amdgcn_s_barrier();
    __builtin_amdgcn_sched_barrier(0);
}

__global__ __launch_bounds__(TPB, 2)
void bispike_kernel(const float* __restrict__ x,
                    const float* __restrict__ decay_p,
                    const float* __restrict__ vth_p,
                    const float* __restrict__ W1,
                    const float* __restrict__ b1,
                    const float* __restrict__ W2,
                    const float* __restrict__ b2,
                    const float* __restrict__ att_w,
                    float* __restrict__ out,
                    char* __restrict__ wsb)
{
    const int tid  = threadIdx.x;
    const int lane = tid & 63;
    const int wid  = tid >> 6;
    const int b    = blockIdx.x & 15;   // XCD-localized: batch b on XCD b%8
    const int bg   = blockIdx.x >> 4;   // 0..15

    const double dec  = 1.0 / (1.0 + exp(-(double)decay_p[0]));
    const double vth  = (double)vth_p[0];
    const double csub = dec * vth;      // loop-invariant spike correction

    double   u[CHK * 4];                // unnormalized membrane m_t (fp64)
    float4   xv[CHK];                   // prefetched x (fp32 in memory)
    unsigned sm[NT];                    // spike bits (32 used)

    {   // t=0: m_0 = x_0 (carry is zero)
        const float* p = x + (size_t)b * FS + (size_t)bg * ELB + tid * 4;
        #pragma unroll
        for (int k = 0; k < CHK; ++k) xv[k] = *(const float4*)(p + k * (TPB * 4));
    }
    double lsum;
    {
        double n0 = 0.0, n1 = 0.0, n2 = 0.0, n3 = 0.0;
        #pragma unroll
        for (int k = 0; k < CHK; ++k) {
            u[k*4+0] = (double)xv[k].x; n0 += fabs(u[k*4+0]);
            u[k*4+1] = (double)xv[k].y; n1 += fabs(u[k*4+1]);
            u[k*4+2] = (double)xv[k].z; n2 += fabs(u[k*4+2]);
            u[k*4+3] = (double)xv[k].w; n3 += fabs(u[k*4+3]);
        }
        lsum = (n0 + n1) + (n2 + n3);
    }

    __shared__ double dred[NW];
    __shared__ double denom_s;

    #pragma unroll 1
    for (int t = 0; t < NT; ++t) {
        // ALL waves prefetch early (rides through raw barriers; wave0's RMW
        // result shares vmcnt with these — they complete concurrently)
        if (t < NT - 1) {
            const float* p = x + ((size_t)(t + 1) * NB + b) * FS
                               + (size_t)bg * ELB + tid * 4;
            #pragma unroll
            for (int k = 0; k < CHK; ++k) xv[k] = *(const float4*)(p + k * (TPB * 4));
        }

        // ---- wave partial of sum |m_t| ----
        double ls = lsum;
        #pragma unroll
        for (int off = 32; off > 0; off >>= 1)
            ls += __shfl_down(ls, off, 64);
        if (lane == 0) dred[wid] = ls;
        bar_lds();

        if (wid == 0) {
            if (lane == 0) {
                const double bs = (((dred[0] + dred[1]) + (dred[2] + dred[3]))
                                 + ((dred[4] + dred[5]) + (dred[6] + dred[7])));
                // single relaxed RMW: payload + bias; bias counts arrivals
                double* acc = (double*)(wsb + (size_t)(t * NB + b) * 64);
                double ret = __hip_atomic_fetch_add(acc, bs + K_BIAS,
                                 __ATOMIC_RELAXED, __HIP_MEMORY_SCOPE_AGENT);
                double v = ret + (bs + K_BIAS);
                if (v < TGT_D - 1.0) {          // not last: poll (payload=flag)
                    long it = 0;
                    for (;;) {
                        v = __hip_atomic_load(acc, __ATOMIC_RELAXED,
                                              __HIP_MEMORY_SCOPE_AGENT);
                        if (v >= TGT_D - 1.0) break;
                        if (++it > SPIN_CAP) break;
                        __builtin_amdgcn_s_sleep(2);
                    }
                }
                // mean exact /2^18; order+bias perturbation ~1e-12 relative
                denom_s = (v - TGT_D) / (double)FS + 1e-6;
            }
        }
        bar_lds();
        const double denom = denom_s;

        // fused threshold + advance:
        //   s_t = (u >= vth*D_t);  u' = (dec/D_t)*u + x' - s_t*(dec*vth)
        const double thr = vth * denom;
        const double a   = dec * (1.0 / denom);
        unsigned smt = 0;
        if (t < NT - 1) {
            double n0 = 0.0, n1 = 0.0, n2 = 0.0, n3 = 0.0;
            #pragma unroll
            for (int k = 0; k < CHK; ++k) {
                const double xn0 = (double)xv[k].x, xn1 = (double)xv[k].y,
                             xn2 = (double)xv[k].z, xn3 = (double)xv[k].w;
                double un;
                bool s0 = (u[k*4+0] >= thr); if (s0) smt |= 1u << (k*4+0);
                un = fma(a, u[k*4+0], xn0); if (s0) un -= csub;
                u[k*4+0] = un; n0 += fabs(un);
                bool s1 = (u[k*4+1] >= thr); if (s1) smt |= 1u << (k*4+1);
                un = fma(a, u[k*4+1], xn1); if (s1) un -= csub;
                u[k*4+1] = un; n1 += fabs(un);
                bool s2 = (u[k*4+2] >= thr); if (s2) smt |= 1u << (k*4+2);
                un = fma(a, u[k*4+2], xn2); if (s2) un -= csub;
                u[k*4+2] = un; n2 += fabs(un);
                bool s3 = (u[k*4+3] >= thr); if (s3) smt |= 1u << (k*4+3);
                un = fma(a, u[k*4+3], xn3); if (s3) un -= csub;
                u[k*4+3] = un; n3 += fabs(un);
            }
            lsum = (n0 + n1) + (n2 + n3);
        } else {
            #pragma unroll
            for (int j = 0; j < CHK * 4; ++j)
                if (u[j] >= thr) smt |= 1u << j;
        }
        sm[t] = smt;
    }

    // ---- spike counts per (t,b): exact ints, same fence-free protocol ----
    __shared__ int ired[NT][NW];
    #pragma unroll
    for (int t = 0; t < NT; ++t) {
        int c = __popc(sm[t]);
        #pragma unroll
        for (int off = 32; off > 0; off >>= 1)
            c += __shfl_down(c, off, 64);
        if (lane == 0) ired[t][wid] = c;
    }
    __syncthreads();

    __shared__ int totc_s[NT];
    __shared__ double summ_s[NT];

    if (wid == 0) {
        int* cp = (int*)(wsb + 8192 + (size_t)(lane * NB + b) * 64);
        int v = TGT_I;                   // lanes >= NT: already "done"
        if (lane < NT) {
            int tot = 0;
            #pragma unroll
            for (int w = 0; w < NW; ++w) tot += ired[lane][w];
            int ret = __hip_atomic_fetch_add(cp, tot + B_BIAS,
                          __ATOMIC_RELAXED, __HIP_MEMORY_SCOPE_AGENT);
            v = ret + tot + B_BIAS;
        }
        long it = 0;
        while (!__all(v >= TGT_I)) {
            if (lane < NT && v < TGT_I)
                v = __hip_atomic_load(cp, __ATOMIC_RELAXED,
                                      __HIP_MEMORY_SCOPE_AGENT);
            if (++it > SPIN_CAP) break;
            __builtin_amdgcn_s_sleep(2);
        }
        if (lane < NT) totc_s[lane] = v - TGT_I;   // exact int total
    }
    __syncthreads();
    if (tid < NT)
        summ_s[tid] = (double)totc_s[tid] / (double)FS;    // exact
    __syncthreads();

    // ---- tiny MLP attention in fp64, redundantly per block ----
    __shared__ double h_s[4 * 64];
    __shared__ double wmat_s[NT];
    if (tid < 256) {
        int nh = tid >> 6, hd = tid & 63;
        double acc = 0.0;
        #pragma unroll
        for (int t = 0; t < NT; ++t)
            acc += summ_s[t] * (double)W1[nh * 512 + hd * 8 + t];
        acc += (double)b1[nh * 64 + hd];
        h_s[tid] = fmax(acc, 0.0);
    }
    __syncthreads();
    if (tid < NT) {
        double w = 0.0;
        for (int nh = 0; nh < 4; ++nh) {
            double macc = 0.0;
            for (int hd = 0; hd < 64; ++hd)
                macc += h_s[nh * 64 + hd] * (double)W2[nh * 512 + tid * 64 + hd];
            macc += (double)b2[nh * 8 + tid];
            w += macc * (double)att_w[nh];
        }
        wmat_s[tid] = w;
    }
    __syncthreads();

    // softmax over t in fp64 (per-thread copy)
    double awr[NT];
    {
        double mx = wmat_s[0];
        #pragma unroll
        for (int t = 1; t < NT; ++t) mx = fmax(mx, wmat_s[t]);
        double ss = 0.0;
        #pragma unroll
        for (int t = 0; t < NT; ++t) { awr[t] = exp(wmat_s[t] - mx); ss += awr[t]; }
        #pragma unroll
        for (int t = 0; t < NT; ++t) awr[t] = awr[t] / ss;
    }

    // ---- out[b,f] = sum_t spike_bit * aw[t,b] (fp64 acc, fp32 store) ----
    float* po = out + (size_t)b * FS + (size_t)bg * ELB + tid * 4;
    #pragma unroll
    for (int k = 0; k < CHK; ++k) {
        double o[4] = {0.0, 0.0, 0.0, 0.0};
        #pragma unroll
        for (int t = 0; t < NT; ++t) {
            const unsigned smt = sm[t];
            o[0] += ((smt >> (k * 4 + 0)) & 1) ? awr[t] : 0.0;
            o[1] += ((smt >> (k * 4 + 1)) & 1) ? awr[t] : 0.0;
            o[2] += ((smt >> (k * 4 + 2)) & 1) ? awr[t] : 0.0;
            o[3] += ((smt >> (k * 4 + 3)) & 1) ? awr[t] : 0.0;
        }
        *(float4*)(po + k * (TPB * 4)) =
            make_float4((float)o[0], (float)o[1], (float)o[2], (float)o[3]);
    }
}

__global__ void diag_kernel(float* out, int code) {
    out[0] = 100000.0f + (float)code;
}

extern "C" void kernel_launch(void* const* d_in, const int* in_sizes, int n_in,
                              void* d_out, int out_size, void* d_ws, size_t ws_size,
                              hipStream_t stream) {
    const float* x     = (const float*)d_in[0];
    const float* decay = (const float*)d_in[1];
    const float* vth   = (const float*)d_in[2];
    const float* W1    = (const float*)d_in[3];
    const float* b1    = (const float*)d_in[4];
    const float* W2    = (const float*)d_in[5];
    const float* b2    = (const float*)d_in[6];
    const float* att   = (const float*)d_in[7];
    float* out = (float*)d_out;

    if (ws_size < WS_NEED) {
        diag_kernel<<<1, 1, 0, stream>>>(out, 999);
        return;
    }

    hipMemsetAsync(d_ws, 0, WS_NEED, stream);

    hipGetLastError();  // clear stale error
    bispike_kernel<<<dim3(GRID), dim3(TPB), 0, stream>>>(
        x, decay, vth, W1, b1, W2, b2, att, out, (char*)d_ws);
    hipError_t err = hipGetLastError();
    if (err != hipSuccess) {
        diag_kernel<<<1, 1, 0, stream>>>(out, (int)err);
    }
}